// Round 1
// baseline (33106.757 us; speedup 1.0000x reference)
//
#include <hip/hip_runtime.h>
#include <hip/hip_cooperative_groups.h>
#include <math.h>

namespace cg = cooperative_groups;

#define HDIM 1024
#define G4   4096
#define VDIM 50257
#define NBLK 256
#define NTHR 256

__device__ __forceinline__ float dot4(float4 a, float4 b) {
  return a.x * b.x + a.y * b.y + a.z * b.z + a.w * b.w;
}

__device__ __forceinline__ float wred(float v) {
#pragma unroll
  for (int off = 32; off > 0; off >>= 1) v += __shfl_xor(v, off);
  return v;
}

__global__ void __launch_bounds__(NTHR)
seq2seq_kernel(const int* __restrict__ source, int S,
               const int* __restrict__ n_steps_p, const int* __restrict__ start_tok_p,
               const float* __restrict__ Wemb_enc,
               const float* __restrict__ W_ih_e, const float* __restrict__ W_hh_e,
               const float* __restrict__ b_ih_e, const float* __restrict__ b_hh_e,
               const float* __restrict__ Wemb_dec,
               const float* __restrict__ W_ih_d, const float* __restrict__ W_hh_d,
               const float* __restrict__ b_ih_d, const float* __restrict__ b_hh_d,
               const float* __restrict__ W_out, const float* __restrict__ b_out,
               float* __restrict__ out,
               float* gates_ws, float* pmax_v, int* pmax_i, float* psum)
{
  cg::grid_group grid = cg::this_grid();
  const int tid  = threadIdx.x;
  const int blk  = blockIdx.x;
  const int wave = tid >> 6;
  const int lane = tid & 63;

  __shared__ float x_lds[HDIM];
  __shared__ float h_lds[HDIM];
  __shared__ float c_lds[HDIM];
  __shared__ float e_lds[224];
  __shared__ float rv[NTHR];
  __shared__ int   ri[NTHR];

  for (int j = tid; j < HDIM; j += NTHR) { h_lds[j] = 0.f; c_lds[j] = 0.f; }
  __syncthreads();

  int buf = 0;
  const int rbase = blk * 16 + wave * 4;

  // ================= encoder =================
  for (int t = 0; t < S; ++t) {
    int tok = source[t];
    ((float4*)x_lds)[tid] = ((const float4*)(Wemb_enc + (size_t)tok * HDIM))[tid];
    __syncthreads();
    {
      const float4* xv  = (const float4*)x_lds;
      const float4* hv  = (const float4*)h_lds;
      const float4* wi0 = (const float4*)(W_ih_e + (size_t)(rbase + 0) * HDIM);
      const float4* wi1 = (const float4*)(W_ih_e + (size_t)(rbase + 1) * HDIM);
      const float4* wi2 = (const float4*)(W_ih_e + (size_t)(rbase + 2) * HDIM);
      const float4* wi3 = (const float4*)(W_ih_e + (size_t)(rbase + 3) * HDIM);
      const float4* wh0 = (const float4*)(W_hh_e + (size_t)(rbase + 0) * HDIM);
      const float4* wh1 = (const float4*)(W_hh_e + (size_t)(rbase + 1) * HDIM);
      const float4* wh2 = (const float4*)(W_hh_e + (size_t)(rbase + 2) * HDIM);
      const float4* wh3 = (const float4*)(W_hh_e + (size_t)(rbase + 3) * HDIM);
      float g0 = 0.f, g1 = 0.f, g2 = 0.f, g3 = 0.f;
#pragma unroll
      for (int k = lane; k < HDIM / 4; k += 64) {
        float4 xx = xv[k], hh = hv[k];
        g0 += dot4(wi0[k], xx) + dot4(wh0[k], hh);
        g1 += dot4(wi1[k], xx) + dot4(wh1[k], hh);
        g2 += dot4(wi2[k], xx) + dot4(wh2[k], hh);
        g3 += dot4(wi3[k], xx) + dot4(wh3[k], hh);
      }
      g0 = wred(g0); g1 = wred(g1); g2 = wred(g2); g3 = wred(g3);
      float* go = gates_ws + buf * G4;
      if (lane == 0) {
        go[rbase + 0] = g0 + b_ih_e[rbase + 0] + b_hh_e[rbase + 0];
        go[rbase + 1] = g1 + b_ih_e[rbase + 1] + b_hh_e[rbase + 1];
        go[rbase + 2] = g2 + b_ih_e[rbase + 2] + b_hh_e[rbase + 2];
        go[rbase + 3] = g3 + b_ih_e[rbase + 3] + b_hh_e[rbase + 3];
      }
    }
    grid.sync();
    {
      const float* gg = gates_ws + buf * G4;
      for (int j = tid; j < HDIM; j += NTHR) {
        float ig = gg[j], fg = gg[j + 1024], gv = gg[j + 2048], og = gg[j + 3072];
        float ii = 1.f / (1.f + expf(-ig));
        float ff = 1.f / (1.f + expf(-fg));
        float gt = tanhf(gv);
        float oo = 1.f / (1.f + expf(-og));
        float cc = ff * c_lds[j] + ii * gt;
        c_lds[j] = cc;
        h_lds[j] = oo * tanhf(cc);
      }
    }
    buf ^= 1;
    __syncthreads();
  }

  // ================= decoder =================
  const int nsteps = n_steps_p[0];
  int tok = start_tok_p[0];
  const int start = blk * 196 + (blk < 81 ? blk : 81);
  const int count = 196 + (blk < 81 ? 1 : 0);

  for (int t = 0; t < nsteps; ++t) {
    // ---- LSTM cell ----
    ((float4*)x_lds)[tid] = ((const float4*)(Wemb_dec + (size_t)tok * HDIM))[tid];
    __syncthreads();
    {
      const float4* xv  = (const float4*)x_lds;
      const float4* hv  = (const float4*)h_lds;
      const float4* wi0 = (const float4*)(W_ih_d + (size_t)(rbase + 0) * HDIM);
      const float4* wi1 = (const float4*)(W_ih_d + (size_t)(rbase + 1) * HDIM);
      const float4* wi2 = (const float4*)(W_ih_d + (size_t)(rbase + 2) * HDIM);
      const float4* wi3 = (const float4*)(W_ih_d + (size_t)(rbase + 3) * HDIM);
      const float4* wh0 = (const float4*)(W_hh_d + (size_t)(rbase + 0) * HDIM);
      const float4* wh1 = (const float4*)(W_hh_d + (size_t)(rbase + 1) * HDIM);
      const float4* wh2 = (const float4*)(W_hh_d + (size_t)(rbase + 2) * HDIM);
      const float4* wh3 = (const float4*)(W_hh_d + (size_t)(rbase + 3) * HDIM);
      float g0 = 0.f, g1 = 0.f, g2 = 0.f, g3 = 0.f;
#pragma unroll
      for (int k = lane; k < HDIM / 4; k += 64) {
        float4 xx = xv[k], hh = hv[k];
        g0 += dot4(wi0[k], xx) + dot4(wh0[k], hh);
        g1 += dot4(wi1[k], xx) + dot4(wh1[k], hh);
        g2 += dot4(wi2[k], xx) + dot4(wh2[k], hh);
        g3 += dot4(wi3[k], xx) + dot4(wh3[k], hh);
      }
      g0 = wred(g0); g1 = wred(g1); g2 = wred(g2); g3 = wred(g3);
      float* go = gates_ws + buf * G4;
      if (lane == 0) {
        go[rbase + 0] = g0 + b_ih_d[rbase + 0] + b_hh_d[rbase + 0];
        go[rbase + 1] = g1 + b_ih_d[rbase + 1] + b_hh_d[rbase + 1];
        go[rbase + 2] = g2 + b_ih_d[rbase + 2] + b_hh_d[rbase + 2];
        go[rbase + 3] = g3 + b_ih_d[rbase + 3] + b_hh_d[rbase + 3];
      }
    }
    grid.sync();  // (A)
    {
      const float* gg = gates_ws + buf * G4;
      for (int j = tid; j < HDIM; j += NTHR) {
        float ig = gg[j], fg = gg[j + 1024], gv = gg[j + 2048], og = gg[j + 3072];
        float ii = 1.f / (1.f + expf(-ig));
        float ff = 1.f / (1.f + expf(-fg));
        float gt = tanhf(gv);
        float oo = 1.f / (1.f + expf(-og));
        float cc = ff * c_lds[j] + ii * gt;
        c_lds[j] = cc;
        h_lds[j] = oo * tanhf(cc);
      }
    }
    buf ^= 1;
    __syncthreads();

    // ---- logits: rows [start, start+count) ----
    {
      const float4* hv = (const float4*)h_lds;
      for (int j = wave; j < count; j += 16) {
        int r0  = start + j;
        int rr1 = (j + 4  < count) ? (start + j + 4)  : r0;
        int rr2 = (j + 8  < count) ? (start + j + 8)  : r0;
        int rr3 = (j + 12 < count) ? (start + j + 12) : r0;
        const float4* w0 = (const float4*)(W_out + (size_t)r0  * HDIM);
        const float4* w1 = (const float4*)(W_out + (size_t)rr1 * HDIM);
        const float4* w2 = (const float4*)(W_out + (size_t)rr2 * HDIM);
        const float4* w3 = (const float4*)(W_out + (size_t)rr3 * HDIM);
        float a0 = 0.f, a1 = 0.f, a2 = 0.f, a3 = 0.f;
#pragma unroll
        for (int k = lane; k < HDIM / 4; k += 64) {
          float4 xx = hv[k];
          a0 += dot4(w0[k], xx);
          a1 += dot4(w1[k], xx);
          a2 += dot4(w2[k], xx);
          a3 += dot4(w3[k], xx);
        }
        a0 = wred(a0); a1 = wred(a1); a2 = wred(a2); a3 = wred(a3);
        if (lane == 0) {
          e_lds[j] = a0 + b_out[r0];
          if (j + 4  < count) e_lds[j + 4]  = a1 + b_out[rr1];
          if (j + 8  < count) e_lds[j + 8]  = a2 + b_out[rr2];
          if (j + 12 < count) e_lds[j + 12] = a3 + b_out[rr3];
        }
      }
    }
    __syncthreads();

    // ---- block-local max/argmax (first-index tie-break, like np.argmax) ----
    {
      float v = -INFINITY; int idx = 0x7fffffff;
      if (tid < count) { v = e_lds[tid]; idx = start + tid; }
      rv[tid] = v; ri[tid] = idx;
    }
    __syncthreads();
#pragma unroll
    for (int s = NTHR / 2; s > 0; s >>= 1) {
      if (tid < s) {
        float v2 = rv[tid + s]; int i2 = ri[tid + s];
        if (v2 > rv[tid] || (v2 == rv[tid] && i2 < ri[tid])) { rv[tid] = v2; ri[tid] = i2; }
      }
      __syncthreads();
    }
    float m_loc = rv[0]; int i_loc = ri[0];
    __syncthreads();

    // ---- block-local sum of exp(l - m_loc); stash exp in e_lds ----
    {
      float e = 0.f;
      if (tid < count) { e = expf(e_lds[tid] - m_loc); e_lds[tid] = e; }
      rv[tid] = e;
    }
    __syncthreads();
#pragma unroll
    for (int s = NTHR / 2; s > 0; s >>= 1) {
      if (tid < s) rv[tid] += rv[tid + s];
      __syncthreads();
    }
    if (tid == 0) { pmax_v[blk] = m_loc; pmax_i[blk] = i_loc; psum[blk] = rv[0]; }
    grid.sync();  // (B)

    // ---- global max/argmax over 256 block partials (redundant per block) ----
    rv[tid] = pmax_v[tid]; ri[tid] = pmax_i[tid];
    __syncthreads();
#pragma unroll
    for (int s = NTHR / 2; s > 0; s >>= 1) {
      if (tid < s) {
        float v2 = rv[tid + s]; int i2 = ri[tid + s];
        if (v2 > rv[tid] || (v2 == rv[tid] && i2 < ri[tid])) { rv[tid] = v2; ri[tid] = i2; }
      }
      __syncthreads();
    }
    float lmax = rv[0]; int tok_next = ri[0];
    __syncthreads();

    // ---- global sum: S = sum_b psum[b] * exp(m_b - lmax) ----
    rv[tid] = psum[tid] * expf(pmax_v[tid] - lmax);
    __syncthreads();
#pragma unroll
    for (int s = NTHR / 2; s > 0; s >>= 1) {
      if (tid < s) rv[tid] += rv[tid + s];
      __syncthreads();
    }
    float Ssum = rv[0];

    // ---- write probs + token ----
    float scale = expf(m_loc - lmax) / Ssum;
    if (tid < count)
      out[(size_t)nsteps + (size_t)t * VDIM + start + tid] = e_lds[tid] * scale;
    if (blk == 0 && tid == 0) out[t] = (float)tok_next;
    tok = tok_next;
  }
}

extern "C" void kernel_launch(void* const* d_in, const int* in_sizes, int n_in,
                              void* d_out, int out_size, void* d_ws, size_t ws_size,
                              hipStream_t stream) {
  const int*   source      = (const int*)d_in[0];
  const int*   n_steps_p   = (const int*)d_in[1];
  const int*   start_tok_p = (const int*)d_in[2];
  const float* Wemb_enc    = (const float*)d_in[3];
  const float* W_ih_e      = (const float*)d_in[4];
  const float* W_hh_e      = (const float*)d_in[5];
  const float* b_ih_e      = (const float*)d_in[6];
  const float* b_hh_e      = (const float*)d_in[7];
  const float* Wemb_dec    = (const float*)d_in[8];
  const float* W_ih_d      = (const float*)d_in[9];
  const float* W_hh_d      = (const float*)d_in[10];
  const float* b_ih_d      = (const float*)d_in[11];
  const float* b_hh_d      = (const float*)d_in[12];
  const float* W_out       = (const float*)d_in[13];
  const float* b_out       = (const float*)d_in[14];
  float*       out         = (float*)d_out;
  int          S           = in_sizes[0];

  char*  ws       = (char*)d_ws;
  float* gates_ws = (float*)ws;                       // 2 * 4096 floats
  float* pmax_v   = (float*)(ws + 2 * G4 * 4);        // 256 floats
  int*   pmax_i   = (int*)  (ws + 2 * G4 * 4 + NBLK * 4);
  float* psum     = (float*)(ws + 2 * G4 * 4 + 2 * NBLK * 4);

  void* args[] = { &source, &S, &n_steps_p, &start_tok_p, &Wemb_enc,
                   &W_ih_e, &W_hh_e, &b_ih_e, &b_hh_e, &Wemb_dec,
                   &W_ih_d, &W_hh_d, &b_ih_d, &b_hh_d, &W_out, &b_out,
                   &out, &gates_ws, &pmax_v, &pmax_i, &psum };

  hipLaunchCooperativeKernel((void*)seq2seq_kernel, dim3(NBLK), dim3(NTHR),
                             args, 0, stream);
}

// Round 2
// 19769.525 us; speedup vs baseline: 1.6746x; 1.6746x over previous
//
#include <hip/hip_runtime.h>
#include <math.h>

#define HDIM 1024
#define G4   4096
#define VDIM 50257
#define NBLK 256
#define NTHR 512

__device__ __forceinline__ float dot4(float4 a, float4 b) {
  return a.x * b.x + a.y * b.y + a.z * b.z + a.w * b.w;
}

__device__ __forceinline__ float wred32(float v) {
  v += __shfl_xor(v, 16); v += __shfl_xor(v, 8); v += __shfl_xor(v, 4);
  v += __shfl_xor(v, 2);  v += __shfl_xor(v, 1);
  return v;
}

__device__ __forceinline__ float wred64(float v) {
  v += __shfl_xor(v, 32); v += __shfl_xor(v, 16); v += __shfl_xor(v, 8);
  v += __shfl_xor(v, 4);  v += __shfl_xor(v, 2);  v += __shfl_xor(v, 1);
  return v;
}

__device__ __forceinline__ void wmax64(float& v, int& i) {
#pragma unroll
  for (int off = 32; off > 0; off >>= 1) {
    float v2 = __shfl_xor(v, off);
    int   i2 = __shfl_xor(i, off);
    if (v2 > v || (v2 == v && i2 < i)) { v = v2; i = i2; }
  }
}

// 2-level monotonic grid barrier. 8 sub-counters (one per blk&7 group of 32
// blocks, 128 B apart) feed one root counter. Round r complete <=> root >= 8r.
// Safe because no block can arrive for round r+1 before root >= 8r.
__device__ __forceinline__ void gbar(unsigned long long* subc,
                                     unsigned long long* root, int r) {
  __syncthreads();
  if (threadIdx.x == 0) {
    __threadfence();  // publish prior writes (agent scope)
    unsigned long long v = __hip_atomic_fetch_add(
        &subc[(blockIdx.x & 7) * 16], 1ull, __ATOMIC_ACQ_REL,
        __HIP_MEMORY_SCOPE_AGENT);
    if (v + 1 == (unsigned long long)r * 32)
      __hip_atomic_fetch_add(root, 1ull, __ATOMIC_ACQ_REL,
                             __HIP_MEMORY_SCOPE_AGENT);
    unsigned long long target = (unsigned long long)r * 8;
    while (__hip_atomic_load(root, __ATOMIC_ACQUIRE,
                             __HIP_MEMORY_SCOPE_AGENT) < target)
      __builtin_amdgcn_s_sleep(2);
    __threadfence();  // acquire side
  }
  __syncthreads();
}

__global__ void __launch_bounds__(NTHR, 2)
seq2seq_kernel(const int* __restrict__ source, int S,
               const int* __restrict__ n_steps_p, const int* __restrict__ start_tok_p,
               const float* __restrict__ Wemb_enc,
               const float* __restrict__ W_ih_e, const float* __restrict__ W_hh_e,
               const float* __restrict__ b_ih_e, const float* __restrict__ b_hh_e,
               const float* __restrict__ Wemb_dec,
               const float* __restrict__ W_ih_d, const float* __restrict__ W_hh_d,
               const float* __restrict__ b_ih_d, const float* __restrict__ b_hh_d,
               const float* __restrict__ W_out, const float* __restrict__ b_out,
               float* __restrict__ out,
               float* gates, float* pmax_v, int* pmax_i, float* psum,
               unsigned long long* subc, unsigned long long* root)
{
  const int tid  = threadIdx.x;
  const int blk  = blockIdx.x;
  const int wave = tid >> 6;
  const int lane = tid & 63;
  const int l32  = lane & 31;
  const int rh   = lane >> 5;   // which of the wave's 2 rows

  __shared__ float4 x4[2][HDIM / 4];
  __shared__ float4 h4[HDIM / 4];
  __shared__ float  c_lds[HDIM];
  __shared__ float  e_lds[256];
  __shared__ float  red_v[8];
  __shared__ int    red_i[8];
  __shared__ float  red_s[8];

  float* h_s = (float*)h4;

  for (int j = tid; j < HDIM; j += NTHR) { h_s[j] = 0.f; c_lds[j] = 0.f; }

  // ---- pin encoder LSTM weight slice in VGPRs (16 float4 / thread) ----
  const int r_e = blk * 16 + wave * 2 + rh;
  float4 wie[8], whe[8];
  {
    const float4* pie = (const float4*)(W_ih_e + (size_t)r_e * HDIM);
    const float4* phe = (const float4*)(W_hh_e + (size_t)r_e * HDIM);
#pragma unroll
    for (int c = 0; c < 8; ++c) { wie[c] = pie[l32 + 32 * c]; whe[c] = phe[l32 + 32 * c]; }
  }
  const float bse = b_ih_e[r_e] + b_hh_e[r_e];

  // stage x[0]
  if (tid < 256)
    x4[0][tid] = ((const float4*)(Wemb_enc + (size_t)source[0] * HDIM))[tid];
  __syncthreads();

  int rnd = 0;
  int gstep = 0;
  int xb = 0;

  // ================= encoder =================
  for (int t = 0; t < S; ++t) {
    // prefetch next x row (completes during FMA + barrier spin)
    float4 pf;
    const bool havepf = (t + 1 < S) && (tid < 256);
    if (havepf)
      pf = ((const float4*)(Wemb_enc + (size_t)source[t + 1] * HDIM))[tid];

    float g = bse;
#pragma unroll
    for (int c = 0; c < 8; ++c) {
      g += dot4(wie[c], x4[xb][l32 + 32 * c]);
      g += dot4(whe[c], h4[l32 + 32 * c]);
    }
    g = wred32(g);
    float* gcur = gates + (gstep & 1) * G4;
    if (l32 == 0) gcur[r_e] = g;

    gbar(subc, root, ++rnd);

    // h/c update (redundant per block)
#pragma unroll
    for (int q = 0; q < 2; ++q) {
      int j = tid + q * NTHR;
      float ig = gcur[j], fg = gcur[j + 1024], gv = gcur[j + 2048], og = gcur[j + 3072];
      float ii = 1.f / (1.f + expf(-ig));
      float ff = 1.f / (1.f + expf(-fg));
      float gt = tanhf(gv);
      float oo = 1.f / (1.f + expf(-og));
      float cc = ff * c_lds[j] + ii * gt;
      c_lds[j] = cc;
      h_s[j]   = oo * tanhf(cc);
    }
    if (havepf) x4[xb ^ 1][tid] = pf;
    __syncthreads();
    xb ^= 1;
    ++gstep;
  }

  // ================= decoder =================
  const int nsteps = n_steps_p[0];
  const int r_d = blk * 16 + wave * 2 + rh;
  const float bsd = b_ih_d[r_d] + b_hh_d[r_d];
  const float4* pid = (const float4*)(W_ih_d + (size_t)r_d * HDIM);
  const float4* phd = (const float4*)(W_hh_d + (size_t)r_d * HDIM);

  const int start = blk * 196 + (blk < 81 ? blk : 81);
  const int count = 196 + (blk < 81 ? 1 : 0);

  float4 pfx;
  {
    int tok0 = start_tok_p[0];
    if (tid < 256)
      pfx = ((const float4*)(Wemb_dec + (size_t)tok0 * HDIM))[tid];
  }

  for (int t = 0; t < nsteps; ++t) {
    // ---- stage x = Wemb_dec[tok] (prefetched last iteration) ----
    if (tid < 256) x4[0][tid] = pfx;
    __syncthreads();

    // ---- LSTM gates (weights streamed; 16 f4 loads in flight) ----
    {
      float g = bsd;
#pragma unroll
      for (int c = 0; c < 8; ++c) {
        g += dot4(pid[l32 + 32 * c], x4[0][l32 + 32 * c]);
        g += dot4(phd[l32 + 32 * c], h4[l32 + 32 * c]);
      }
      g = wred32(g);
      float* gcur = gates + (gstep & 1) * G4;
      if (l32 == 0) gcur[r_d] = g;
    }
    gbar(subc, root, ++rnd);  // (A)
    {
      const float* gcur = gates + (gstep & 1) * G4;
#pragma unroll
      for (int q = 0; q < 2; ++q) {
        int j = tid + q * NTHR;
        float ig = gcur[j], fg = gcur[j + 1024], gv = gcur[j + 2048], og = gcur[j + 3072];
        float ii = 1.f / (1.f + expf(-ig));
        float ff = 1.f / (1.f + expf(-fg));
        float gt = tanhf(gv);
        float oo = 1.f / (1.f + expf(-og));
        float cc = ff * c_lds[j] + ii * gt;
        c_lds[j] = cc;
        h_s[j]   = oo * tanhf(cc);
      }
    }
    ++gstep;
    __syncthreads();

    // ---- logits: 8-row batches per wave, 32 f4 loads in flight ----
    {
      const float4* h4p = (const float4*)h4;
      for (int i = 0; i < 4; ++i) {
        int jb = wave + 64 * i;
        if (jb >= count) break;
        const float4* wp[8];
        float bo[8];
        int   jr[8];
#pragma unroll
        for (int k = 0; k < 8; ++k) {
          int j = jb + 8 * k;
          jr[k] = j;
          int rr = start + ((j < count) ? j : jb);
          wp[k] = (const float4*)(W_out + (size_t)rr * HDIM);
          bo[k] = b_out[rr];
        }
        float acc[8] = {0.f, 0.f, 0.f, 0.f, 0.f, 0.f, 0.f, 0.f};
#pragma unroll
        for (int kk = 0; kk < 4; ++kk) {
          float4 hh = h4p[lane + 64 * kk];
#pragma unroll
          for (int k = 0; k < 8; ++k) acc[k] += dot4(wp[k][lane + 64 * kk], hh);
        }
#pragma unroll
        for (int k = 0; k < 8; ++k) {
          float s = wred64(acc[k]);
          if (lane == 0 && jr[k] < count) e_lds[jr[k]] = s + bo[k];
        }
      }
    }
    __syncthreads();

    // ---- block-local max/argmax (np.argmax tie-break: lowest index) ----
    float m_loc; int i_loc;
    {
      float v = -INFINITY; int idx = 0x7fffffff;
      if (tid < count) { v = e_lds[tid]; idx = start + tid; }
      wmax64(v, idx);
      if (lane == 0) { red_v[wave] = v; red_i[wave] = idx; }
      __syncthreads();
      m_loc = red_v[0]; i_loc = red_i[0];
#pragma unroll
      for (int w = 1; w < 8; ++w) {
        float v2 = red_v[w]; int i2 = red_i[w];
        if (v2 > m_loc || (v2 == m_loc && i2 < i_loc)) { m_loc = v2; i_loc = i2; }
      }
    }

    // ---- block-local sum of exp(l - m_loc); keep own exp in register ----
    float pe = 0.f;
    if (tid < count) pe = expf(e_lds[tid] - m_loc);
    {
      float ls = wred64(pe);
      if (lane == 0) red_s[wave] = ls;
    }
    __syncthreads();
    float lsum = 0.f;
#pragma unroll
    for (int w = 0; w < 8; ++w) lsum += red_s[w];

    if (tid == 0) { pmax_v[blk] = m_loc; pmax_i[blk] = i_loc; psum[blk] = lsum; }
    gbar(subc, root, ++rnd);  // (B)

    // ---- global max/argmax + sum (redundant per block, deterministic) ----
    float lmax; int tokn;
    {
      float v = -INFINITY; int idx = 0x7fffffff;
      if (tid < NBLK) { v = pmax_v[tid]; idx = pmax_i[tid]; }
      wmax64(v, idx);
      if (lane == 0) { red_v[wave] = v; red_i[wave] = idx; }
      __syncthreads();
      lmax = red_v[0]; tokn = red_i[0];
#pragma unroll
      for (int w = 1; w < 8; ++w) {
        float v2 = red_v[w]; int i2 = red_i[w];
        if (v2 > lmax || (v2 == lmax && i2 < tokn)) { lmax = v2; tokn = i2; }
      }
    }
    {
      float s = (tid < NBLK) ? psum[tid] * expf(pmax_v[tid] - lmax) : 0.f;
      s = wred64(s);
      if (lane == 0) red_s[wave] = s;
    }
    __syncthreads();
    float Ssum = 0.f;
#pragma unroll
    for (int w = 0; w < 8; ++w) Ssum += red_s[w];

    // prefetch next token's embedding row (hides under stores + next barrier)
    if (tid < 256)
      pfx = ((const float4*)(Wemb_dec + (size_t)tokn * HDIM))[tid];

    // ---- write probs + token ----
    float scale = expf(m_loc - lmax) / Ssum;
    if (tid < count)
      out[(size_t)nsteps + (size_t)t * VDIM + start + tid] = pe * scale;
    if (blk == 0 && tid == 0) out[t] = (float)tokn;
  }
}

extern "C" void kernel_launch(void* const* d_in, const int* in_sizes, int n_in,
                              void* d_out, int out_size, void* d_ws, size_t ws_size,
                              hipStream_t stream) {
  const int*   source      = (const int*)d_in[0];
  const int*   n_steps_p   = (const int*)d_in[1];
  const int*   start_tok_p = (const int*)d_in[2];
  const float* Wemb_enc    = (const float*)d_in[3];
  const float* W_ih_e      = (const float*)d_in[4];
  const float* W_hh_e      = (const float*)d_in[5];
  const float* b_ih_e      = (const float*)d_in[6];
  const float* b_hh_e      = (const float*)d_in[7];
  const float* Wemb_dec    = (const float*)d_in[8];
  const float* W_ih_d      = (const float*)d_in[9];
  const float* W_hh_d      = (const float*)d_in[10];
  const float* b_ih_d      = (const float*)d_in[11];
  const float* b_hh_d      = (const float*)d_in[12];
  const float* W_out       = (const float*)d_in[13];
  const float* b_out       = (const float*)d_in[14];
  float*       out         = (float*)d_out;
  int          S           = in_sizes[0];

  char* ws = (char*)d_ws;
  float*              gates  = (float*)(ws);                    // 32768 B
  float*              pmax_v = (float*)(ws + 32768);            // 1024 B
  int*                pmax_i = (int*)  (ws + 33792);            // 1024 B
  float*              psum   = (float*)(ws + 34816);            // 1024 B
  unsigned long long* subc   = (unsigned long long*)(ws + 35840); // 1024 B
  unsigned long long* root   = (unsigned long long*)(ws + 36864); // 128 B

  // zero barrier counters (and partials) every launch -> replay-deterministic
  hipMemsetAsync(ws + 32768, 0, 4224, stream);

  void* args[] = { &source, &S, &n_steps_p, &start_tok_p, &Wemb_enc,
                   &W_ih_e, &W_hh_e, &b_ih_e, &b_hh_e, &Wemb_dec,
                   &W_ih_d, &W_hh_d, &b_ih_d, &b_hh_d, &W_out, &b_out,
                   &out, &gates, &pmax_v, &pmax_i, &psum, &subc, &root };

  hipLaunchCooperativeKernel((void*)seq2seq_kernel, dim3(NBLK), dim3(NTHR),
                             args, 0, stream);
}